// Round 1
// 1040.630 us; speedup vs baseline: 1.3503x; 1.3503x over previous
//
#include <hip/hip_runtime.h>
#include <math.h>

#define TT 2048      // tokens = B*S
#define HH 1024      // hidden
#define EE 8         // experts
#define II 4096      // intermediate
#define VV 32000     // vocab

typedef __attribute__((ext_vector_type(8))) short short8;
typedef __attribute__((ext_vector_type(4))) float f32x4;
typedef __attribute__((ext_vector_type(4))) unsigned short us4;

__device__ __forceinline__ unsigned short f2bf(float f) {
  union { float f; unsigned u; } v; v.f = f;
  unsigned r = (v.u + 0x7FFFu + ((v.u >> 16) & 1u)) >> 16;
  return (unsigned short)r;
}

// async global->LDS, 16B per lane. LDS dest must be wave-uniform base; HW adds lane*16.
__device__ __forceinline__ void gl2lds16(const void* g, void* l) {
  __builtin_amdgcn_global_load_lds(
      (__attribute__((address_space(1))) void*)(g),
      (__attribute__((address_space(3))) void*)(l),
      16, 0, 0);
}

// ---------------- K0: tiled transpose + f32->bf16  out[C][R] = bf16(in[R][C]) ----------------
__global__ __launch_bounds__(256) void k_transpose(
    const float* __restrict__ in, unsigned short* __restrict__ out,
    int R, int C, size_t ibs, size_t obs)
{
  __shared__ unsigned short tl[64][72];   // 64x64 tile, padded rows (144B) vs bank aliasing
  const int tid = threadIdx.x;
  const int c0 = blockIdx.x * 64;
  const int r0 = blockIdx.y * 64;
  const float* ip = in + (size_t)blockIdx.z * ibs;
  unsigned short* op = out + (size_t)blockIdx.z * obs;
  const int rl = tid >> 4;          // 0..15
  const int cc = (tid & 15) * 4;    // 0..60
#pragma unroll
  for (int p = 0; p < 4; p++) {
    const float4 v = *(const float4*)&ip[(size_t)(r0 + p*16 + rl)*C + c0 + cc];
    tl[cc+0][p*16+rl] = f2bf(v.x);
    tl[cc+1][p*16+rl] = f2bf(v.y);
    tl[cc+2][p*16+rl] = f2bf(v.z);
    tl[cc+3][p*16+rl] = f2bf(v.w);
  }
  __syncthreads();
  const int cl = tid >> 2;          // out-row (= original col) 0..63
  const int hc = (tid & 3) * 16;    // 16-short chunk
  int4* dst = (int4*)&op[(size_t)(c0 + cl)*R + r0 + hc];
  dst[0] = *(int4*)&tl[cl][hc];
  dst[1] = *(int4*)&tl[cl][hc + 8];
}

// ---------------- K1: embedding gather + router + top2 + softmax ----------------
__global__ __launch_bounds__(64) void k_gather_router(
    const int* __restrict__ ids, const float* __restrict__ emb,
    const float* __restrict__ rw, const float* __restrict__ rb,
    unsigned short* __restrict__ xb, float* __restrict__ rweights,
    float* __restrict__ sel, int* __restrict__ counts, int* __restrict__ tok_list,
    int* __restrict__ tinfo)
{
  const int t = blockIdx.x;
  const int lane = threadIdx.x;
  const int tok = ids[t];
  float p[EE];
#pragma unroll
  for (int e = 0; e < EE; e++) p[e] = 0.f;
#pragma unroll
  for (int c = 0; c < 4; c++) {
    const int h = c*256 + lane*4;
    const float4 xv = *(const float4*)&emb[tok*HH + h];
    us4 u;
    u[0] = f2bf(xv.x); u[1] = f2bf(xv.y); u[2] = f2bf(xv.z); u[3] = f2bf(xv.w);
    *(us4*)&xb[t*HH + h] = u;
    const float xs[4] = {xv.x, xv.y, xv.z, xv.w};
#pragma unroll
    for (int j = 0; j < 4; j++) {
      const float4 r0 = *(const float4*)&rw[(h+j)*EE];
      const float4 r1 = *(const float4*)&rw[(h+j)*EE + 4];
      p[0] += xs[j]*r0.x; p[1] += xs[j]*r0.y; p[2] += xs[j]*r0.z; p[3] += xs[j]*r0.w;
      p[4] += xs[j]*r1.x; p[5] += xs[j]*r1.y; p[6] += xs[j]*r1.z; p[7] += xs[j]*r1.w;
    }
  }
#pragma unroll
  for (int off = 32; off >= 1; off >>= 1) {
#pragma unroll
    for (int e = 0; e < EE; e++) p[e] += __shfl_xor(p[e], off, 64);
  }
  if (lane == 0) {
#pragma unroll
    for (int e = 0; e < EE; e++) p[e] += rb[e];
    int b0 = 0; float v0 = p[0];
#pragma unroll
    for (int e = 1; e < EE; e++) { if (p[e] > v0) { v0 = p[e]; b0 = e; } }
    int b1 = -1; float v1 = -3.0e38f;
#pragma unroll
    for (int e = 0; e < EE; e++) { if (e != b0 && p[e] > v1) { v1 = p[e]; b1 = e; } }
    const float ex = expf(v1 - v0);          // v0 >= v1 -> ex in (0,1]
    const float w0 = 1.f / (1.f + ex);
    const float w1v = ex * w0;
    rweights[t*2]   = w0;
    rweights[t*2+1] = w1v;
    sel[t*2]   = (float)b0;
    sel[t*2+1] = (float)b1;
    int j0 = atomicAdd(&counts[b0], 1); tok_list[b0*TT + j0] = t;
    int j1 = atomicAdd(&counts[b1], 1); tok_list[b1*TT + j1] = t;
    int4 ti; ti.x = b0; ti.y = j0; ti.z = b1; ti.w = j1;
    *(int4*)&tinfo[t*4] = ti;
  }
}

// ---------------- K1b: exclusive prefix scan of expert counts ----------------
__global__ void k_scan(const int* __restrict__ counts, int* __restrict__ offsets) {
  int s = 0;
  for (int e = 0; e < EE; e++) { offsets[e] = s; s += counts[e]; }
}

// ---------------- K2: expert GEMM1 + bias + exact gelu -> h_buf (bf16) ----------------
// C[Te, II] = gelu(X_e[Te, HH] @ w1t[e]^T + b1[e]); A rows gathered via tok_list
__global__ __launch_bounds__(256) void k_ffn1(
    const unsigned short* __restrict__ xb, const unsigned short* __restrict__ w1t,
    const float* __restrict__ b1, const int* __restrict__ counts,
    const int* __restrict__ offsets, const int* __restrict__ tok_list,
    unsigned short* __restrict__ hbuf)
{
  const int e = blockIdx.z;
  const int Te = counts[e];
  const int m0 = blockIdx.y * 128;
  if (m0 >= Te) return;
  const int n0 = blockIdx.x * 128;

  __shared__ short As[128*32];
  __shared__ short Bs[128*32];
  const int tid = threadIdx.x;
  const int lane = tid & 63, wid = tid >> 6;
  const int wm = (wid & 1)*64, wn = (wid >> 1)*64;
  const int l15 = lane & 15, quad = lane >> 4;

  // staging mapping: row = tid>>2 (+64 for second call), 16B chunk = tid&3
  const int srow = tid >> 2, schk = (tid & 3) * 8;
  const int gr0 = m0 + srow, gr1 = gr0 + 64;
  const int tok0 = (gr0 < Te) ? tok_list[e*TT + gr0] : 0;
  const int tok1 = (gr1 < Te) ? tok_list[e*TT + gr1] : 0;
  const unsigned short* a0p = xb + (size_t)tok0*HH + schk;
  const unsigned short* a1p = xb + (size_t)tok1*HH + schk;
  const unsigned short* b0p = w1t + ((size_t)e*II + n0 + srow)*HH + schk;
  const unsigned short* b1p = b0p + (size_t)64*HH;
  short* aL0 = &As[(wid*16)*32];
  short* aL1 = &As[(64 + wid*16)*32];
  short* bL0 = &Bs[(wid*16)*32];
  short* bL1 = &Bs[(64 + wid*16)*32];

  f32x4 acc[4][4];
  const f32x4 zf = {0.f, 0.f, 0.f, 0.f};
#pragma unroll
  for (int i = 0; i < 4; i++)
#pragma unroll
    for (int j = 0; j < 4; j++) acc[i][j] = zf;

  for (int k0 = 0; k0 < HH; k0 += 32) {
    gl2lds16(a0p + k0, aL0);
    gl2lds16(a1p + k0, aL1);
    gl2lds16(b0p + k0, bL0);
    gl2lds16(b1p + k0, bL1);
    __syncthreads();
    short8 af[4], bfr[4];
#pragma unroll
    for (int i = 0; i < 4; i++) af[i]  = *(const short8*)&As[(wm + i*16 + l15)*32 + quad*8];
#pragma unroll
    for (int i = 0; i < 4; i++) bfr[i] = *(const short8*)&Bs[(wn + i*16 + l15)*32 + quad*8];
#pragma unroll
    for (int i = 0; i < 4; i++)
#pragma unroll
      for (int j = 0; j < 4; j++)
        acc[i][j] = __builtin_amdgcn_mfma_f32_16x16x32_bf16(af[i], bfr[j], acc[i][j], 0, 0, 0);
    __syncthreads();
  }

  const int base = offsets[e];
#pragma unroll
  for (int i = 0; i < 4; i++) {
#pragma unroll
    for (int j = 0; j < 4; j++) {
      const int col = n0 + wn + j*16 + l15;
      const float bb = b1[e*II + col];
#pragma unroll
      for (int r = 0; r < 4; r++) {
        const int rl = m0 + wm + i*16 + quad*4 + r;
        if (rl < Te) {
          float v = acc[i][j][r] + bb;
          v = 0.5f * v * (1.f + erff(v * 0.70710678118654752f));
          hbuf[(size_t)(base + rl)*II + col] = f2bf(v);
        }
      }
    }
  }
}

// ---------------- K3: expert GEMM2 + bias -> ybuf[slot] (f32, no atomics) ----------------
__global__ __launch_bounds__(256) void k_ffn2(
    const unsigned short* __restrict__ hbuf, const unsigned short* __restrict__ w2t,
    const float* __restrict__ b2, const int* __restrict__ counts,
    const int* __restrict__ offsets, float* __restrict__ ybuf)
{
  const int e = blockIdx.z;
  const int Te = counts[e];
  const int m0 = blockIdx.y * 128;
  if (m0 >= Te) return;
  const int n0 = blockIdx.x * 128;

  __shared__ short As[128*32];
  __shared__ short Bs[128*32];
  const int tid = threadIdx.x;
  const int lane = tid & 63, wid = tid >> 6;
  const int wm = (wid & 1)*64, wn = (wid >> 1)*64;
  const int l15 = lane & 15, quad = lane >> 4;

  const int srow = tid >> 2, schk = (tid & 3) * 8;
  const int base = offsets[e];
  int h0row = base + m0 + srow;      if (h0row > 2*TT - 1) h0row = 2*TT - 1;
  int h1row = base + m0 + 64 + srow; if (h1row > 2*TT - 1) h1row = 2*TT - 1;
  const unsigned short* a0p = hbuf + (size_t)h0row*II + schk;
  const unsigned short* a1p = hbuf + (size_t)h1row*II + schk;
  const unsigned short* b0p = w2t + ((size_t)e*HH + n0 + srow)*II + schk;
  const unsigned short* b1p = b0p + (size_t)64*II;
  short* aL0 = &As[(wid*16)*32];
  short* aL1 = &As[(64 + wid*16)*32];
  short* bL0 = &Bs[(wid*16)*32];
  short* bL1 = &Bs[(64 + wid*16)*32];

  f32x4 acc[4][4];
  const f32x4 zf = {0.f, 0.f, 0.f, 0.f};
#pragma unroll
  for (int i = 0; i < 4; i++)
#pragma unroll
    for (int j = 0; j < 4; j++) acc[i][j] = zf;

  for (int k0 = 0; k0 < II; k0 += 32) {
    gl2lds16(a0p + k0, aL0);
    gl2lds16(a1p + k0, aL1);
    gl2lds16(b0p + k0, bL0);
    gl2lds16(b1p + k0, bL1);
    __syncthreads();
    short8 af[4], bfr[4];
#pragma unroll
    for (int i = 0; i < 4; i++) af[i]  = *(const short8*)&As[(wm + i*16 + l15)*32 + quad*8];
#pragma unroll
    for (int i = 0; i < 4; i++) bfr[i] = *(const short8*)&Bs[(wn + i*16 + l15)*32 + quad*8];
#pragma unroll
    for (int i = 0; i < 4; i++)
#pragma unroll
      for (int j = 0; j < 4; j++)
        acc[i][j] = __builtin_amdgcn_mfma_f32_16x16x32_bf16(af[i], bfr[j], acc[i][j], 0, 0, 0);
    __syncthreads();
  }

#pragma unroll
  for (int i = 0; i < 4; i++) {
#pragma unroll
    for (int j = 0; j < 4; j++) {
      const int col = n0 + wn + j*16 + l15;
      const float bb = b2[e*HH + col];
#pragma unroll
      for (int r = 0; r < 4; r++) {
        const int rl = m0 + wm + i*16 + quad*4 + r;
        if (rl < Te) ybuf[(size_t)(base + rl)*HH + col] = acc[i][j][r] + bb;
      }
    }
  }
}

// ---------------- K4: combine each token's two expert slots -> bf16 ----------------
__global__ __launch_bounds__(256) void k_combine(
    const float* __restrict__ ybuf, const int* __restrict__ offsets,
    const int* __restrict__ tinfo, unsigned short* __restrict__ xoutb)
{
  const int t = blockIdx.x;
  const int4 ti = *(const int4*)&tinfo[t*4];
  const int s0 = offsets[ti.x] + ti.y;
  const int s1 = offsets[ti.z] + ti.w;
  const int i = threadIdx.x * 4;
  const float4 a = *(const float4*)&ybuf[(size_t)s0*HH + i];
  const float4 b = *(const float4*)&ybuf[(size_t)s1*HH + i];
  us4 u;
  u[0] = f2bf(a.x + b.x); u[1] = f2bf(a.y + b.y);
  u[2] = f2bf(a.z + b.z); u[3] = f2bf(a.w + b.w);
  *(us4*)&xoutb[(size_t)t*HH + i] = u;
}

// ---------------- K5: LM head GEMM  C[TT,VV] = X[TT,HH] @ lmwt^T + lm_b ----------------
__global__ __launch_bounds__(256) void k_lmhead(
    const unsigned short* __restrict__ A, const unsigned short* __restrict__ lmwt,
    const float* __restrict__ bias, float* __restrict__ out)
{
  __shared__ short As[128*32];
  __shared__ short Bs[128*32];
  const int tid = threadIdx.x;
  const int m0 = blockIdx.x*128, n0 = blockIdx.y*128;
  const int lane = tid & 63, wid = tid >> 6;
  const int wm = (wid & 1)*64, wn = (wid >> 1)*64;
  const int l15 = lane & 15, quad = lane >> 4;

  const int srow = tid >> 2, schk = (tid & 3) * 8;
  const unsigned short* a0p = A + (size_t)(m0 + srow)*HH + schk;
  const unsigned short* a1p = a0p + (size_t)64*HH;
  const unsigned short* b0p = lmwt + (size_t)(n0 + srow)*HH + schk;
  const unsigned short* b1p = b0p + (size_t)64*HH;
  short* aL0 = &As[(wid*16)*32];
  short* aL1 = &As[(64 + wid*16)*32];
  short* bL0 = &Bs[(wid*16)*32];
  short* bL1 = &Bs[(64 + wid*16)*32];

  f32x4 acc[4][4];
  const f32x4 zf = {0.f, 0.f, 0.f, 0.f};
#pragma unroll
  for (int i = 0; i < 4; i++)
#pragma unroll
    for (int j = 0; j < 4; j++) acc[i][j] = zf;

  for (int k0 = 0; k0 < HH; k0 += 32) {
    gl2lds16(a0p + k0, aL0);
    gl2lds16(a1p + k0, aL1);
    gl2lds16(b0p + k0, bL0);
    gl2lds16(b1p + k0, bL1);
    __syncthreads();
    short8 af[4], bfr[4];
#pragma unroll
    for (int i = 0; i < 4; i++) af[i]  = *(const short8*)&As[(wm + i*16 + l15)*32 + quad*8];
#pragma unroll
    for (int i = 0; i < 4; i++) bfr[i] = *(const short8*)&Bs[(wn + i*16 + l15)*32 + quad*8];
#pragma unroll
    for (int i = 0; i < 4; i++)
#pragma unroll
      for (int j = 0; j < 4; j++)
        acc[i][j] = __builtin_amdgcn_mfma_f32_16x16x32_bf16(af[i], bfr[j], acc[i][j], 0, 0, 0);
    __syncthreads();
  }

#pragma unroll
  for (int i = 0; i < 4; i++) {
#pragma unroll
    for (int j = 0; j < 4; j++) {
      const int col = n0 + wn + j*16 + l15;
      const float bb = bias[col];
#pragma unroll
      for (int r = 0; r < 4; r++) {
        const int row = m0 + wm + i*16 + quad*4 + r;
        out[(size_t)row*VV + col] = acc[i][j][r] + bb;
      }
    }
  }
}

extern "C" void kernel_launch(void* const* d_in, const int* in_sizes, int n_in,
                              void* d_out, int out_size, void* d_ws, size_t ws_size,
                              hipStream_t stream) {
  const int*   ids = (const int*)d_in[0];
  const float* emb = (const float*)d_in[1];
  const float* rw  = (const float*)d_in[2];
  const float* rb  = (const float*)d_in[3];
  const float* w1  = (const float*)d_in[4];
  const float* b1  = (const float*)d_in[5];
  const float* w2  = (const float*)d_in[6];
  const float* b2  = (const float*)d_in[7];
  const float* lmw = (const float*)d_in[8];
  const float* lmb = (const float*)d_in[9];

  // ---- workspace (~70.6 MB) ----
  char* ws = (char*)d_ws;
  unsigned short* xb    = (unsigned short*)(ws);                        // 4 MiB  [TT,HH] bf16
  unsigned short* xoutb = (unsigned short*)(ws + 4194304);              // 4 MiB  [TT,HH] bf16
  unsigned short* lmwt  = (unsigned short*)(ws + 8388608);              // 65,536,000 B [VV,HH] bf16
  int* counts   = (int*)(ws + 8388608 + 65536000);                      // 16 ints
  int* offsets  = counts + 16;                                          // 16 ints
  int* tinfo    = counts + 32;                                          // TT*4 ints {e0,j0,e1,j1}
  int* tok_list = tinfo + TT*4;                                         // EE*TT ints

  // ---- transient buffers live in d_out's logits region (all dead before k_lmhead) ----
  char* ob = (char*)d_out;
  float* logits   = (float*)ob;
  float* rweights = (float*)(ob + (size_t)TT*VV*4);                     // after logits
  float* sel      = rweights + TT*2;
  unsigned short* w1t  = (unsigned short*)(ob);                         // 64 MiB  [E,II,HH] bf16
  unsigned short* w2t  = (unsigned short*)(ob + 67108864);              // 64 MiB  [E,HH,II] bf16
  unsigned short* hbuf = (unsigned short*)(ob + 134217728);             // 32 MiB  [2*TT,II] bf16
  float*          ybuf = (float*)(ob + 167772160);                      // 16 MiB  [2*TT,HH] f32
  // ends at 184,549,376 < 262,144,000 (logits size) -- safe.

  hipMemsetAsync(counts, 0, 64, stream);

  k_gather_router<<<TT, 64, 0, stream>>>(ids, emb, rw, rb, xb, rweights, sel,
                                         counts, tok_list, tinfo);
  k_scan<<<1, 1, 0, stream>>>(counts, offsets);

  // one-time bf16 transposed weight caches
  k_transpose<<<dim3(II/64, HH/64, EE), 256, 0, stream>>>(w1, w1t, HH, II,
                                                          (size_t)HH*II, (size_t)HH*II);
  k_transpose<<<dim3(HH/64, II/64, EE), 256, 0, stream>>>(w2, w2t, II, HH,
                                                          (size_t)II*HH, (size_t)II*HH);
  k_transpose<<<dim3(VV/64, HH/64, 1), 256, 0, stream>>>(lmw, lmwt, HH, VV, 0, 0);

  k_ffn1<<<dim3(II/128, TT/128, EE), 256, 0, stream>>>(xb, w1t, b1, counts, offsets,
                                                       tok_list, hbuf);
  k_ffn2<<<dim3(HH/128, TT/128, EE), 256, 0, stream>>>(hbuf, w2t, b2, counts, offsets, ybuf);
  k_combine<<<TT, 256, 0, stream>>>(ybuf, offsets, tinfo, xoutb);
  k_lmhead<<<dim3(TT/128, VV/128), 256, 0, stream>>>(xoutb, lmwt, lmb, logits);
}

// Round 2
// 970.750 us; speedup vs baseline: 1.4475x; 1.0720x over previous
//
#include <hip/hip_runtime.h>
#include <math.h>

#define TT 2048      // tokens = B*S
#define HH 1024      // hidden
#define EE 8         // experts
#define II 4096      // intermediate
#define VV 32000     // vocab

typedef __attribute__((ext_vector_type(8))) short short8;
typedef __attribute__((ext_vector_type(4))) float f32x4;
typedef __attribute__((ext_vector_type(4))) unsigned short us4;

__device__ __forceinline__ unsigned short f2bf(float f) {
  union { float f; unsigned u; } v; v.f = f;
  unsigned r = (v.u + 0x7FFFu + ((v.u >> 16) & 1u)) >> 16;
  return (unsigned short)r;
}

// async global->LDS, 16B per lane. LDS dest must be wave-uniform base; HW adds lane*16.
__device__ __forceinline__ void gl2lds16(const void* g, void* l) {
  __builtin_amdgcn_global_load_lds(
      (__attribute__((address_space(1))) void*)(g),
      (__attribute__((address_space(3))) void*)(l),
      16, 0, 0);
}

// ---------------- K0: tiled transpose + f32->bf16  out[C][R] = bf16(in[R][C]) ----------------
__global__ __launch_bounds__(256) void k_transpose(
    const float* __restrict__ in, unsigned short* __restrict__ out,
    int R, int C, size_t ibs, size_t obs)
{
  __shared__ unsigned short tl[64][72];
  const int tid = threadIdx.x;
  const int c0 = blockIdx.x * 64;
  const int r0 = blockIdx.y * 64;
  const float* ip = in + (size_t)blockIdx.z * ibs;
  unsigned short* op = out + (size_t)blockIdx.z * obs;
  const int rl = tid >> 4;
  const int cc = (tid & 15) * 4;
#pragma unroll
  for (int p = 0; p < 4; p++) {
    const float4 v = *(const float4*)&ip[(size_t)(r0 + p*16 + rl)*C + c0 + cc];
    tl[cc+0][p*16+rl] = f2bf(v.x);
    tl[cc+1][p*16+rl] = f2bf(v.y);
    tl[cc+2][p*16+rl] = f2bf(v.z);
    tl[cc+3][p*16+rl] = f2bf(v.w);
  }
  __syncthreads();
  const int cl = tid >> 2;
  const int hc = (tid & 3) * 16;
  int4* dst = (int4*)&op[(size_t)(c0 + cl)*R + r0 + hc];
  dst[0] = *(int4*)&tl[cl][hc];
  dst[1] = *(int4*)&tl[cl][hc + 8];
}

// ---------------- K1: embedding gather + router + top2 + softmax ----------------
__global__ __launch_bounds__(64) void k_gather_router(
    const int* __restrict__ ids, const float* __restrict__ emb,
    const float* __restrict__ rw, const float* __restrict__ rb,
    unsigned short* __restrict__ xb, float* __restrict__ rweights,
    float* __restrict__ sel, int* __restrict__ counts, int* __restrict__ tok_list,
    int* __restrict__ tinfo)
{
  const int t = blockIdx.x;
  const int lane = threadIdx.x;
  const int tok = ids[t];
  float p[EE];
#pragma unroll
  for (int e = 0; e < EE; e++) p[e] = 0.f;
#pragma unroll
  for (int c = 0; c < 4; c++) {
    const int h = c*256 + lane*4;
    const float4 xv = *(const float4*)&emb[tok*HH + h];
    us4 u;
    u[0] = f2bf(xv.x); u[1] = f2bf(xv.y); u[2] = f2bf(xv.z); u[3] = f2bf(xv.w);
    *(us4*)&xb[t*HH + h] = u;
    const float xs[4] = {xv.x, xv.y, xv.z, xv.w};
#pragma unroll
    for (int j = 0; j < 4; j++) {
      const float4 r0 = *(const float4*)&rw[(h+j)*EE];
      const float4 r1 = *(const float4*)&rw[(h+j)*EE + 4];
      p[0] += xs[j]*r0.x; p[1] += xs[j]*r0.y; p[2] += xs[j]*r0.z; p[3] += xs[j]*r0.w;
      p[4] += xs[j]*r1.x; p[5] += xs[j]*r1.y; p[6] += xs[j]*r1.z; p[7] += xs[j]*r1.w;
    }
  }
#pragma unroll
  for (int off = 32; off >= 1; off >>= 1) {
#pragma unroll
    for (int e = 0; e < EE; e++) p[e] += __shfl_xor(p[e], off, 64);
  }
  if (lane == 0) {
#pragma unroll
    for (int e = 0; e < EE; e++) p[e] += rb[e];
    int b0 = 0; float v0 = p[0];
#pragma unroll
    for (int e = 1; e < EE; e++) { if (p[e] > v0) { v0 = p[e]; b0 = e; } }
    int b1 = -1; float v1 = -3.0e38f;
#pragma unroll
    for (int e = 0; e < EE; e++) { if (e != b0 && p[e] > v1) { v1 = p[e]; b1 = e; } }
    const float ex = expf(v1 - v0);
    const float w0 = 1.f / (1.f + ex);
    const float w1v = ex * w0;
    rweights[t*2]   = w0;
    rweights[t*2+1] = w1v;
    sel[t*2]   = (float)b0;
    sel[t*2+1] = (float)b1;
    int j0 = atomicAdd(&counts[b0], 1); tok_list[b0*TT + j0] = t;
    int j1 = atomicAdd(&counts[b1], 1); tok_list[b1*TT + j1] = t;
    int4 ti; ti.x = b0; ti.y = j0; ti.z = b1; ti.w = j1;
    *(int4*)&tinfo[t*4] = ti;
  }
}

// ---------------- K1b: exclusive prefix scan of expert counts ----------------
__global__ void k_scan(const int* __restrict__ counts, int* __restrict__ offsets) {
  int s = 0;
  for (int e = 0; e < EE; e++) { offsets[e] = s; s += counts[e]; }
}

// ---------------- K2: expert GEMM1 + bias + exact gelu -> h_buf (bf16) ----------------
__global__ __launch_bounds__(256) void k_ffn1(
    const unsigned short* __restrict__ xb, const unsigned short* __restrict__ w1t,
    const float* __restrict__ b1, const int* __restrict__ counts,
    const int* __restrict__ offsets, const int* __restrict__ tok_list,
    unsigned short* __restrict__ hbuf)
{
  const int e = blockIdx.z;
  const int Te = counts[e];
  const int m0 = blockIdx.y * 128;
  if (m0 >= Te) return;
  const int n0 = blockIdx.x * 128;

  __shared__ short As[2][128*32];
  __shared__ short Bs[2][128*32];
  const int tid = threadIdx.x;
  const int lane = tid & 63, wid = tid >> 6;
  const int wm = (wid & 1)*64, wn = (wid >> 1)*64;
  const int l15 = lane & 15, quad = lane >> 4;
  const int srow = tid >> 2, schk = (tid & 3) * 8;

  const int gr0 = m0 + srow, gr1 = gr0 + 64;
  const int tok0 = (gr0 < Te) ? tok_list[e*TT + gr0] : 0;
  const int tok1 = (gr1 < Te) ? tok_list[e*TT + gr1] : 0;
  const unsigned short* a0p = xb + (size_t)tok0*HH + schk;
  const unsigned short* a1p = xb + (size_t)tok1*HH + schk;
  const unsigned short* b0p = w1t + ((size_t)e*II + n0 + srow)*HH + schk;
  const unsigned short* b1p = b0p + (size_t)64*HH;
  const int w16 = (wid*16)*32;

  f32x4 acc[4][4];
  const f32x4 zf = {0.f, 0.f, 0.f, 0.f};
#pragma unroll
  for (int i = 0; i < 4; i++)
#pragma unroll
    for (int j = 0; j < 4; j++) acc[i][j] = zf;

  short* Ac = &As[0][0]; short* An = &As[1][0];
  short* Bc = &Bs[0][0]; short* Bn = &Bs[1][0];

  auto compute = [&](const short* Ab, const short* Bb) {
    short8 af[4], bfr[4];
#pragma unroll
    for (int i = 0; i < 4; i++) af[i]  = *(const short8*)&Ab[(wm + i*16 + l15)*32 + quad*8];
#pragma unroll
    for (int i = 0; i < 4; i++) bfr[i] = *(const short8*)&Bb[(wn + i*16 + l15)*32 + quad*8];
#pragma unroll
    for (int i = 0; i < 4; i++)
#pragma unroll
      for (int j = 0; j < 4; j++)
        acc[i][j] = __builtin_amdgcn_mfma_f32_16x16x32_bf16(af[i], bfr[j], acc[i][j], 0, 0, 0);
  };

  // prologue: stage k=0
  gl2lds16(a0p, Ac + w16);
  gl2lds16(a1p, Ac + 64*32 + w16);
  gl2lds16(b0p, Bc + w16);
  gl2lds16(b1p, Bc + 64*32 + w16);
  __syncthreads();

  for (int t = 0; t < 31; t++) {
    const int kn = (t + 1) * 32;
    gl2lds16(a0p + kn, An + w16);
    gl2lds16(a1p + kn, An + 64*32 + w16);
    gl2lds16(b0p + kn, Bn + w16);
    gl2lds16(b1p + kn, Bn + 64*32 + w16);
    compute(Ac, Bc);
    __syncthreads();
    short* tp = Ac; Ac = An; An = tp;
    tp = Bc; Bc = Bn; Bn = tp;
  }
  compute(Ac, Bc);

  const int base = offsets[e];
#pragma unroll
  for (int i = 0; i < 4; i++) {
#pragma unroll
    for (int j = 0; j < 4; j++) {
      const int col = n0 + wn + j*16 + l15;
      const float bb = b1[e*II + col];
#pragma unroll
      for (int r = 0; r < 4; r++) {
        const int rl = m0 + wm + i*16 + quad*4 + r;
        if (rl < Te) {
          float v = acc[i][j][r] + bb;
          v = 0.5f * v * (1.f + erff(v * 0.70710678118654752f));
          hbuf[(size_t)(base + rl)*II + col] = f2bf(v);
        }
      }
    }
  }
}

// ---------------- K3: expert GEMM2, split-K x4, partials -> ybuf slabs (f32) ----------------
__global__ __launch_bounds__(256) void k_ffn2(
    const unsigned short* __restrict__ hbuf, const unsigned short* __restrict__ w2t,
    const int* __restrict__ counts, const int* __restrict__ offsets,
    float* __restrict__ ybuf)
{
  const int e = blockIdx.z >> 2, kc = blockIdx.z & 3;
  const int Te = counts[e];
  const int m0 = blockIdx.y * 128;
  if (m0 >= Te) return;
  const int n0 = blockIdx.x * 128;

  __shared__ short As[2][128*32];
  __shared__ short Bs[2][128*32];
  const int tid = threadIdx.x;
  const int lane = tid & 63, wid = tid >> 6;
  const int wm = (wid & 1)*64, wn = (wid >> 1)*64;
  const int l15 = lane & 15, quad = lane >> 4;
  const int srow = tid >> 2, schk = (tid & 3) * 8;

  const int base = offsets[e];
  int h0row = base + m0 + srow;      if (h0row > 2*TT - 1) h0row = 2*TT - 1;
  int h1row = base + m0 + 64 + srow; if (h1row > 2*TT - 1) h1row = 2*TT - 1;
  const unsigned short* a0p = hbuf + (size_t)h0row*II + kc*1024 + schk;
  const unsigned short* a1p = hbuf + (size_t)h1row*II + kc*1024 + schk;
  const unsigned short* b0p = w2t + ((size_t)e*HH + n0 + srow)*II + kc*1024 + schk;
  const unsigned short* b1p = b0p + (size_t)64*II;
  const int w16 = (wid*16)*32;

  f32x4 acc[4][4];
  const f32x4 zf = {0.f, 0.f, 0.f, 0.f};
#pragma unroll
  for (int i = 0; i < 4; i++)
#pragma unroll
    for (int j = 0; j < 4; j++) acc[i][j] = zf;

  short* Ac = &As[0][0]; short* An = &As[1][0];
  short* Bc = &Bs[0][0]; short* Bn = &Bs[1][0];

  auto compute = [&](const short* Ab, const short* Bb) {
    short8 af[4], bfr[4];
#pragma unroll
    for (int i = 0; i < 4; i++) af[i]  = *(const short8*)&Ab[(wm + i*16 + l15)*32 + quad*8];
#pragma unroll
    for (int i = 0; i < 4; i++) bfr[i] = *(const short8*)&Bb[(wn + i*16 + l15)*32 + quad*8];
#pragma unroll
    for (int i = 0; i < 4; i++)
#pragma unroll
      for (int j = 0; j < 4; j++)
        acc[i][j] = __builtin_amdgcn_mfma_f32_16x16x32_bf16(af[i], bfr[j], acc[i][j], 0, 0, 0);
  };

  gl2lds16(a0p, Ac + w16);
  gl2lds16(a1p, Ac + 64*32 + w16);
  gl2lds16(b0p, Bc + w16);
  gl2lds16(b1p, Bc + 64*32 + w16);
  __syncthreads();

  for (int t = 0; t < 31; t++) {
    const int kn = (t + 1) * 32;
    gl2lds16(a0p + kn, An + w16);
    gl2lds16(a1p + kn, An + 64*32 + w16);
    gl2lds16(b0p + kn, Bn + w16);
    gl2lds16(b1p + kn, Bn + 64*32 + w16);
    compute(Ac, Bc);
    __syncthreads();
    short* tp = Ac; Ac = An; An = tp;
    tp = Bc; Bc = Bn; Bn = tp;
  }
  compute(Ac, Bc);

  float* yp = ybuf + (size_t)kc * 2*TT*HH;
#pragma unroll
  for (int i = 0; i < 4; i++) {
#pragma unroll
    for (int j = 0; j < 4; j++) {
      const int col = n0 + wn + j*16 + l15;
#pragma unroll
      for (int r = 0; r < 4; r++) {
        const int rl = m0 + wm + i*16 + quad*4 + r;
        if (rl < Te) yp[(size_t)(base + rl)*HH + col] = acc[i][j][r];
      }
    }
  }
}

// ---------------- K4: combine token's two expert slots (4 partials each) + biases -> bf16 ----------------
__global__ __launch_bounds__(256) void k_combine(
    const float* __restrict__ ybuf, const float* __restrict__ b2,
    const int* __restrict__ offsets, const int* __restrict__ tinfo,
    unsigned short* __restrict__ xoutb)
{
  const int t = blockIdx.x;
  const int4 ti = *(const int4*)&tinfo[t*4];
  const size_t s0 = (size_t)(offsets[ti.x] + ti.y) * HH;
  const size_t s1 = (size_t)(offsets[ti.z] + ti.w) * HH;
  const int i = threadIdx.x * 4;
  const float4 c0 = *(const float4*)&b2[ti.x*HH + i];
  const float4 c1 = *(const float4*)&b2[ti.z*HH + i];
  float sx = c0.x + c1.x, sy = c0.y + c1.y, sz = c0.z + c1.z, sw = c0.w + c1.w;
  const size_t SLAB = (size_t)2*TT*HH;
#pragma unroll
  for (int kc = 0; kc < 4; kc++) {
    const float4 a = *(const float4*)&ybuf[kc*SLAB + s0 + i];
    const float4 b = *(const float4*)&ybuf[kc*SLAB + s1 + i];
    sx += a.x + b.x; sy += a.y + b.y; sz += a.z + b.z; sw += a.w + b.w;
  }
  us4 u;
  u[0] = f2bf(sx); u[1] = f2bf(sy); u[2] = f2bf(sz); u[3] = f2bf(sw);
  *(us4*)&xoutb[(size_t)t*HH + i] = u;
}

// ---------------- K5: LM head GEMM  C[TT,VV] = X[TT,HH] @ lmwt^T + lm_b ----------------
// BM=256, BN=128, BK=32; 512 threads = 8 waves (4m x 2n); 2-phase prefetch; XCD swizzle.
__global__ __launch_bounds__(512) void k_lmhead(
    const unsigned short* __restrict__ A, const unsigned short* __restrict__ lmwt,
    const float* __restrict__ bias, float* __restrict__ out)
{
  __shared__ short As[2][256*32];
  __shared__ short Bs[2][128*32];
  // nwg = 2000 (8 m x 250 n). phys b -> logical so that same-XCD blocks are consecutive
  // and 8 consecutive logicals share one B-panel (m fastest).
  const int b = blockIdx.x;
  const int logical = (b & 7) * 250 + (b >> 3);
  const int m0 = (logical & 7) << 8;     // 0..1792
  const int n0 = (logical >> 3) << 7;    // 0..31872
  const int tid = threadIdx.x;
  const int lane = tid & 63, wid = tid >> 6;
  const int wm = (wid & 3)*64, wn = (wid >> 2)*64;
  const int l15 = lane & 15, quad = lane >> 4;
  const int srow = tid >> 2, schk = (tid & 3) * 8;   // srow 0..127

  const unsigned short* a0p = A + (size_t)(m0 + srow)*HH + schk;
  const unsigned short* a1p = a0p + (size_t)128*HH;
  const unsigned short* b0p = lmwt + (size_t)(n0 + srow)*HH + schk;
  const int w16 = (wid*16)*32;

  f32x4 acc[4][4];
  const f32x4 zf = {0.f, 0.f, 0.f, 0.f};
#pragma unroll
  for (int i = 0; i < 4; i++)
#pragma unroll
    for (int j = 0; j < 4; j++) acc[i][j] = zf;

  short* Ac = &As[0][0]; short* An = &As[1][0];
  short* Bc = &Bs[0][0]; short* Bn = &Bs[1][0];

  auto compute = [&](const short* Ab, const short* Bb) {
    short8 af[4], bfr[4];
#pragma unroll
    for (int i = 0; i < 4; i++) af[i]  = *(const short8*)&Ab[(wm + i*16 + l15)*32 + quad*8];
#pragma unroll
    for (int i = 0; i < 4; i++) bfr[i] = *(const short8*)&Bb[(wn + i*16 + l15)*32 + quad*8];
#pragma unroll
    for (int i = 0; i < 4; i++)
#pragma unroll
      for (int j = 0; j < 4; j++)
        acc[i][j] = __builtin_amdgcn_mfma_f32_16x16x32_bf16(af[i], bfr[j], acc[i][j], 0, 0, 0);
  };

  gl2lds16(a0p, Ac + w16);
  gl2lds16(a1p, Ac + 128*32 + w16);
  gl2lds16(b0p, Bc + w16);
  __syncthreads();

  for (int t = 0; t < 31; t++) {
    const int kn = (t + 1) * 32;
    gl2lds16(a0p + kn, An + w16);
    gl2lds16(a1p + kn, An + 128*32 + w16);
    gl2lds16(b0p + kn, Bn + w16);
    compute(Ac, Bc);
    __syncthreads();
    short* tp = Ac; Ac = An; An = tp;
    tp = Bc; Bc = Bn; Bn = tp;
  }
  compute(Ac, Bc);

#pragma unroll
  for (int i = 0; i < 4; i++) {
#pragma unroll
    for (int j = 0; j < 4; j++) {
      const int col = n0 + wn + j*16 + l15;
      const float bb = bias[col];
#pragma unroll
      for (int r = 0; r < 4; r++) {
        const int row = m0 + wm + i*16 + quad*4 + r;
        out[(size_t)row*VV + col] = acc[i][j][r] + bb;
      }
    }
  }
}

extern "C" void kernel_launch(void* const* d_in, const int* in_sizes, int n_in,
                              void* d_out, int out_size, void* d_ws, size_t ws_size,
                              hipStream_t stream) {
  const int*   ids = (const int*)d_in[0];
  const float* emb = (const float*)d_in[1];
  const float* rw  = (const float*)d_in[2];
  const float* rb  = (const float*)d_in[3];
  const float* w1  = (const float*)d_in[4];
  const float* b1  = (const float*)d_in[5];
  const float* w2  = (const float*)d_in[6];
  const float* b2  = (const float*)d_in[7];
  const float* lmw = (const float*)d_in[8];
  const float* lmb = (const float*)d_in[9];

  // ---- workspace (~74 MB) ----
  char* ws = (char*)d_ws;
  unsigned short* xb    = (unsigned short*)(ws);                        // 4 MiB  [TT,HH] bf16
  unsigned short* xoutb = (unsigned short*)(ws + 4194304);              // 4 MiB  [TT,HH] bf16
  unsigned short* lmwt  = (unsigned short*)(ws + 8388608);              // 65,536,000 B [VV,HH] bf16
  int* counts   = (int*)(ws + 8388608 + 65536000);
  int* offsets  = counts + 16;
  int* tinfo    = counts + 32;                                          // TT*4 ints
  int* tok_list = tinfo + TT*4;                                         // EE*TT ints

  // ---- transient buffers in d_out's logits region (all dead before k_lmhead) ----
  char* ob = (char*)d_out;
  float* logits   = (float*)ob;
  float* rweights = (float*)(ob + (size_t)TT*VV*4);
  float* sel      = rweights + TT*2;
  unsigned short* w1t  = (unsigned short*)(ob);                         // 64 MiB [E,II,HH] bf16
  unsigned short* w2t  = (unsigned short*)(ob + 67108864);              // 64 MiB [E,HH,II] bf16
  unsigned short* hbuf = (unsigned short*)(ob + 134217728);             // 32 MiB [2*TT,II] bf16
  float*          ybuf = (float*)(ob + 167772160);                      // 64 MiB 4x[2*TT,HH] f32
  // ends at 234,881,024 < 262,144,000 (logits bytes) -- safe.

  hipMemsetAsync(counts, 0, 64, stream);

  k_gather_router<<<TT, 64, 0, stream>>>(ids, emb, rw, rb, xb, rweights, sel,
                                         counts, tok_list, tinfo);
  k_scan<<<1, 1, 0, stream>>>(counts, offsets);

  k_transpose<<<dim3(II/64, HH/64, EE), 256, 0, stream>>>(w1, w1t, HH, II,
                                                          (size_t)HH*II, (size_t)HH*II);
  k_transpose<<<dim3(HH/64, II/64, EE), 256, 0, stream>>>(w2, w2t, II, HH,
                                                          (size_t)II*HH, (size_t)II*HH);
  k_transpose<<<dim3(VV/64, HH/64, 1), 256, 0, stream>>>(lmw, lmwt, HH, VV, 0, 0);

  k_ffn1<<<dim3(II/128, TT/128, EE), 256, 0, stream>>>(xb, w1t, b1, counts, offsets,
                                                       tok_list, hbuf);
  k_ffn2<<<dim3(HH/128, TT/128, EE*4), 256, 0, stream>>>(hbuf, w2t, counts, offsets, ybuf);
  k_combine<<<TT, 256, 0, stream>>>(ybuf, b2, offsets, tinfo, xoutb);
  k_lmhead<<<(TT/256)*(VV/128), 512, 0, stream>>>(xoutb, lmwt, lmb, logits);
}